// Round 24
// baseline (345.994 us; speedup 1.0000x reference)
//
#include <hip/hip_runtime.h>
#include <hip/hip_bf16.h>

#define CH   16
#define HID  128
#define DIM  64
#define NVOX (4 * DIM * DIM * DIM)

typedef __attribute__((ext_vector_type(8))) short short8;
typedef __attribute__((ext_vector_type(4))) float f32x4;
typedef __attribute__((ext_vector_type(2))) float f32x2;
typedef __attribute__((ext_vector_type(4))) unsigned int u32x4;

#define MFMA16 __builtin_amdgcn_mfma_f32_16x16x32_bf16

// sched_barrier mask: allow ALU|VALU|SALU|MFMA|DS to cross, pin VMEM above.
#define SB_PIN_VMEM_ONLY 0x38F

// zero row for OOB neighborhood reads (never written; .rodata zeros)
__device__ __align__(16) const float g_zrow[1024] = {};

__device__ __forceinline__ unsigned short f2bf(float f) {
    return __bfloat16_as_ushort(__float2bfloat16(f));   // staging only
}

// native packed cvt: dst = {bf16(hi)<<16 | bf16(lo)} (RNE) -- 1 instr for 2 vals
__device__ __forceinline__ unsigned int cvtpk(float lo, float hi) {
    unsigned int r;
    asm("v_cvt_pk_bf16_f32 %0, %1, %2" : "=v"(r) : "v"(lo), "v"(hi));
    return r;
}
__device__ __forceinline__ short8 as_s8(u32x4 v) {
    return __builtin_bit_cast(short8, v);
}

// ---- forced VOP3P packed-f32 (R19, kept: neutral, not harmful) ----
__device__ __forceinline__ f32x2 pk_add(f32x2 a, f32x2 b) {
    f32x2 r;
    asm("v_pk_add_f32 %0, %1, %2" : "=v"(r) : "v"(a), "v"(b));
    return r;
}
__device__ __forceinline__ f32x2 pk_sub(f32x2 a, f32x2 b) {   // a - b
    f32x2 r;
    asm("v_pk_add_f32 %0, %1, %2 neg_lo:[0,1] neg_hi:[0,1]"
        : "=v"(r) : "v"(a), "v"(b));
    return r;
}
__device__ __forceinline__ f32x2 pk_mul(f32x2 a, f32x2 b) {
    f32x2 r;
    asm("v_pk_mul_f32 %0, %1, %2" : "=v"(r) : "v"(a), "v"(b));
    return r;
}
__device__ __forceinline__ f32x2 pk_fma(f32x2 a, f32x2 b, f32x2 c) { // a*b+c
    f32x2 r;
    asm("v_pk_fma_f32 %0, %1, %2, %3" : "=v"(r) : "v"(a), "v"(b), "v"(c));
    return r;
}

struct V4 { f32x2 lo, hi; };
__device__ __forceinline__ V4 toV4(f32x4 v) {
    return V4{ f32x2{v[0], v[1]}, f32x2{v[2], v[3]} };
}
__device__ __forceinline__ V4 vadd(V4 a, V4 b){
    return V4{ pk_add(a.lo, b.lo), pk_add(a.hi, b.hi) };
}
__device__ __forceinline__ V4 vsub(V4 a, V4 b){
    return V4{ pk_sub(a.lo, b.lo), pk_sub(a.hi, b.hi) };
}
__device__ __forceinline__ V4 vfma2(V4 a, V4 b){       // b + 2*a
    const f32x2 two = {2.0f, 2.0f};
    return V4{ pk_fma(two, a.lo, b.lo), pk_fma(two, a.hi, b.hi) };
}
__device__ __forceinline__ V4 vmask(V4 a, float s){
    const f32x2 ss = {s, s};
    return V4{ pk_mul(a.lo, ss), pk_mul(a.hi, ss) };
}

struct Plane { V4 ps, pda, pds, vb; float pmax; };

// R24: R22's 1024-thread single-block-per-CU structure (PROVEN to force real
// occupancy 43.6% -- the only config that did) with the VGPR clamp fixed via
// DIRECT ATTRIBUTES instead of __launch_bounds__: waves_per_eu(4,4) pins
// exactly 4 waves/SIMD -> VGPR budget 128 >= the ~120 the body needs.
// (launch_bounds heuristic gave 64 -> spill in R4/R6/R22 -- repeatedly.)
// Grid 256 = 1 block/CU; 16 waves = 4 x-tiles x 4 z-chunks, work per wave
// unchanged from R20/R23. Indexing correctness-proven in R22 (absmax OK).
// Register hoist of W-frags abandoned (R14/R15 deterministic miscompile).
__global__
__attribute__((amdgpu_flat_work_group_size(1024, 1024),
               amdgpu_waves_per_eu(4, 4)))
void nca_pass1(
    const float* __restrict__ x,  const float* __restrict__ w1,
    const float* __restrict__ b1, const float* __restrict__ w2,
    const float* __restrict__ b2, const float* __restrict__ ru,
    float* __restrict__ out, float* __restrict__ alpha_new,
    float* __restrict__ pre_life)
{
    __shared__ __align__(16) unsigned short sA1[8192];  // [n][h][g][m][j] 16KB
    __shared__ __align__(16) unsigned short sA2[2048];  // [s][g][m][j]     4KB
    __shared__ __align__(16) float sb1[HID];
    __shared__ __align__(16) float sb2[CH];

    for (int t = threadIdx.x; t < 8192; t += 1024) {
        const int j = t & 7, mm = (t >> 3) & 15, gg = (t >> 7) & 3,
                  hh = (t >> 9) & 1, nn = t >> 10;
        const int op  = 2 * hh + (j & 1);
        const int row = 16 * gg + 4 * (j >> 1) + op;                // kappa1
        float wv = w1[row * HID + 16 * nn + mm];
        if (op) wv *= (1.0f / 32.0f);       // fold sobel 1/32 into W1
        sA1[t] = f2bf(wv);
    }
    for (int t = threadIdx.x; t < 2048; t += 1024) {
        const int j = t & 7, mm = (t >> 3) & 15, gg = (t >> 7) & 3, ss = t >> 9;
        const int kk = 32 * ss + 16 * (j >> 2) + 4 * gg + (j & 3);  // kappa2
        sA2[t] = f2bf(w2[kk * CH + mm]);
    }
    if (threadIdx.x < HID) sb1[threadIdx.x] = b1[threadIdx.x];
    if (threadIdx.x < CH)  sb2[threadIdx.x] = b2[threadIdx.x];
    __syncthreads();

    const int lane = threadIdx.x & 63;
    const int wid  = __builtin_amdgcn_readfirstlane(threadIdx.x >> 6); // 0..15
    const int m = lane & 15;
    const int g = lane >> 4;

    // XCD-chunked swizzle (bijective: 256 % 8 == 0); block = (b, y)
    const unsigned pbid = blockIdx.x;
    const unsigned lbid = (pbid & 7) * 32 + (pbid >> 3);

    const int y  = lbid & 63;
    const int b  = lbid >> 6;
    const int zc = wid >> 2;            // wave's z-chunk (0..3)
    const int z0 = zc << 4;

    const short8* pA1 = ((const short8*)sA1) + (g * 16 + m);
    const short8* pA2 = ((const short8*)sA2) + (g * 16 + m);
    const float*  pb1 = sb1 + 4 * g;
    const float*  pb2 = sb2 + 4 * g;

    const int wx = 16 * (wid & 3) + m;  // wave's x-tile (0..3)
    const float ok0 = (wx > 0)  ? 1.0f : 0.0f;
    const float ok2 = (wx < 63) ? 1.0f : 0.0f;
    const int o1 = wx * CH + 4 * g;
    const int o0 = (wx > 0  ? wx - 1 : 0 ) * CH + 4 * g;
    const int o2 = (wx < 63 ? wx + 1 : 63) * CH + 4 * g;

    f32x4 LA[3][3], LB[3][3];   // two plane tap buffers
    Plane PA{}, PB{}, PC{};

#define LOADP(zz, L) do {                                                     \
    const bool zok = ((unsigned)(zz)) < 64u;                                  \
    const float* bp = x + ((size_t)(b * 64 + (zz))) * 65536;                  \
    const float* r0 = (zok && y > 0)  ? bp + (size_t)(y - 1) * 1024 : g_zrow; \
    const float* r1 =  zok            ? bp + (size_t)y * 1024       : g_zrow; \
    const float* r2 = (zok && y < 63) ? bp + (size_t)(y + 1) * 1024 : g_zrow; \
    L[0][0] = *(const f32x4*)(r0 + o0); L[0][1] = *(const f32x4*)(r0 + o1);   \
    L[0][2] = *(const f32x4*)(r0 + o2);                                       \
    L[1][0] = *(const f32x4*)(r1 + o0); L[1][1] = *(const f32x4*)(r1 + o1);   \
    L[1][2] = *(const f32x4*)(r1 + o2);                                       \
    L[2][0] = *(const f32x4*)(r2 + o0); L[2][1] = *(const f32x4*)(r2 + o1);   \
    L[2][2] = *(const f32x4*)(r2 + o2);                                       \
} while (0)

#define PARTIALS(P, L) do {                                                   \
    V4 s0, s1, s2, d0, d1, d2; float pm;                                      \
    { V4 va = vmask(toV4(L[0][0]), ok0), vb = toV4(L[0][1]),                  \
         vc = vmask(toV4(L[0][2]), ok2);                                      \
      s0 = vfma2(vb, vadd(va, vc)); d0 = vsub(va, vc);                        \
      pm = fmaxf(fmaxf(va.hi[1], vb.hi[1]), vc.hi[1]); }                      \
    { V4 va = vmask(toV4(L[1][0]), ok0), vb = toV4(L[1][1]),                  \
         vc = vmask(toV4(L[1][2]), ok2);                                      \
      s1 = vfma2(vb, vadd(va, vc)); d1 = vsub(va, vc);                        \
      pm = fmaxf(pm, fmaxf(fmaxf(va.hi[1], vb.hi[1]), vc.hi[1]));             \
      (P).vb = vb; }                                                          \
    { V4 va = vmask(toV4(L[2][0]), ok0), vb = toV4(L[2][1]),                  \
         vc = vmask(toV4(L[2][2]), ok2);                                      \
      s2 = vfma2(vb, vadd(va, vc)); d2 = vsub(va, vc);                        \
      pm = fmaxf(pm, fmaxf(fmaxf(va.hi[1], vb.hi[1]), vc.hi[1])); }           \
    (P).ps  = vfma2(s1, vadd(s0, s2));                                        \
    (P).pda = vsub(s0, s2);                                                   \
    (P).pds = vfma2(d1, vadd(d0, d2));                                        \
    (P).pmax = pm;                                                            \
} while (0)

// builds a0_S/a1_S (MFMA B-frags), cen_S, pm_S for one output plane
#define COMBINE(Pm1, P0, Pp1, S)                                              \
    const V4 zA_##S = vsub((Pm1).ps, (Pp1).ps);                               \
    const V4 zB_##S = vfma2((P0).pda, vadd((Pm1).pda, (Pp1).pda));            \
    const V4 zC_##S = vfma2((P0).pds, vadd((Pm1).pds, (Pp1).pds));            \
    const V4 cen_##S = (P0).vb;                                               \
    const float pm_##S = fmaxf(fmaxf((Pm1).pmax, (P0).pmax), (Pp1).pmax);     \
    const u32x4 A0_##S = { cvtpk(cen_##S.lo[0], zA_##S.lo[0]),                \
                           cvtpk(cen_##S.lo[1], zA_##S.lo[1]),                \
                           cvtpk(cen_##S.hi[0], zA_##S.hi[0]),                \
                           cvtpk(cen_##S.hi[1], zA_##S.hi[1]) };              \
    const u32x4 A1_##S = { cvtpk(zB_##S.lo[0], zC_##S.lo[0]),                 \
                           cvtpk(zB_##S.lo[1], zC_##S.lo[1]),                 \
                           cvtpk(zB_##S.hi[0], zC_##S.hi[0]),                 \
                           cvtpk(zB_##S.hi[1], zC_##S.hi[1]) };               \
    const short8 a0_##S = as_s8(A0_##S), a1_##S = as_s8(A1_##S);

#define EPILOG(S, zn, rvc) do {                                               \
    const int vox = ((b * 64 + (zn)) * 64 + y) * 64 + wx;                     \
    const float mk = ((rvc) <= 0.5f) ? 1.0f : 0.0f;                           \
    f32x4 xn;                                                                 \
    xn[0] = fmaf(e##S[0], mk, cen_##S.lo[0]);                                 \
    xn[1] = fmaf(e##S[1], mk, cen_##S.lo[1]);                                 \
    xn[2] = fmaf(e##S[2], mk, cen_##S.hi[0]);                                 \
    xn[3] = fmaf(e##S[3], mk, cen_##S.hi[1]);                                 \
    *(f32x4*)(out + (size_t)vox * CH + 4 * g) = xn;                           \
    if (g == 0) {                                                             \
        alpha_new[vox] = xn[3];                                               \
        pre_life[vox]  = (pm_##S > 0.1f) ? 1.0f : 0.0f;                       \
    }                                                                         \
} while (0)

// one z-PAIR: outputs n and n+1, single pass over W1/W2 LDS fragments
#define STEP2(Pm1, P0, Pp1, n) do {                                           \
    PARTIALS(Pp1, LA);                   /* plane n+1 */                      \
    COMBINE(Pm1, P0, Pp1, 0)             /* output n; Pm1 dead after */       \
    PARTIALS(Pm1, LB);                   /* plane n+2 -> dead slot */         \
    COMBINE(P0, Pp1, Pm1, 1)             /* output n+1 */                     \
    float rvn0 = 0.0f, rvn1 = 0.0f;                                           \
    if ((n) < 14) {                                                           \
        LOADP(z0 + (n) + 3, LA);                                              \
        LOADP(z0 + (n) + 4, LB);                                              \
        rvn0 = ru[((b * 64 + (z0 + (n) + 2)) * 64 + y) * 64 + wx];            \
        rvn1 = ru[((b * 64 + (z0 + (n) + 3)) * 64 + y) * 64 + wx];            \
    }                                                                         \
    __builtin_amdgcn_sched_barrier(SB_PIN_VMEM_ONLY);                         \
    u32x4 Pw0_0={},Pw1_0={},Pw2_0={},Pw3_0={};                                \
    u32x4 Pw0_1={},Pw1_1={},Pw2_1={},Pw3_1={};                                \
    _Pragma("unroll")                                                         \
    for (int nn = 0; nn < 8; nn++) {                                          \
        const short8 wA = pA1[(2 * nn + 0) * 64];   /* read ONCE, use 2x */   \
        const short8 wB = pA1[(2 * nn + 1) * 64];                             \
        const f32x4 bias = *(const f32x4*)(pb1 + 16 * nn);                    \
        f32x4 h0 = bias, h1 = bias;                                           \
        h0 = MFMA16(wA, a0_0, h0, 0, 0, 0); h0 = MFMA16(wB, a1_0, h0, 0, 0, 0); \
        h1 = MFMA16(wA, a0_1, h1, 0, 0, 0); h1 = MFMA16(wB, a1_1, h1, 0, 0, 0); \
        const unsigned w00 = cvtpk(fmaxf(h0[0], 0.0f), fmaxf(h0[1], 0.0f));   \
        const unsigned w01 = cvtpk(fmaxf(h0[2], 0.0f), fmaxf(h0[3], 0.0f));   \
        const unsigned w10 = cvtpk(fmaxf(h1[0], 0.0f), fmaxf(h1[1], 0.0f));   \
        const unsigned w11 = cvtpk(fmaxf(h1[2], 0.0f), fmaxf(h1[3], 0.0f));   \
        const int hi = (nn & 1) << 1;                                         \
        if (nn >> 1 == 0)      { Pw0_0[hi]=w00; Pw0_0[hi+1]=w01;              \
                                 Pw0_1[hi]=w10; Pw0_1[hi+1]=w11; }            \
        else if (nn >> 1 == 1) { Pw1_0[hi]=w00; Pw1_0[hi+1]=w01;              \
                                 Pw1_1[hi]=w10; Pw1_1[hi+1]=w11; }            \
        else if (nn >> 1 == 2) { Pw2_0[hi]=w00; Pw2_0[hi+1]=w01;              \
                                 Pw2_1[hi]=w10; Pw2_1[hi+1]=w11; }            \
        else                   { Pw3_0[hi]=w00; Pw3_0[hi+1]=w01;              \
                                 Pw3_1[hi]=w10; Pw3_1[hi+1]=w11; }            \
    }                                                                         \
    const f32x4 eb = *(const f32x4*)pb2;                                      \
    f32x4 e0 = eb, e1 = eb;                                                   \
    { const short8 wf = pA2[0 * 64];                                          \
      e0 = MFMA16(wf, as_s8(Pw0_0), e0, 0, 0, 0);                             \
      e1 = MFMA16(wf, as_s8(Pw0_1), e1, 0, 0, 0); }                           \
    { const short8 wf = pA2[1 * 64];                                          \
      e0 = MFMA16(wf, as_s8(Pw1_0), e0, 0, 0, 0);                             \
      e1 = MFMA16(wf, as_s8(Pw1_1), e1, 0, 0, 0); }                           \
    { const short8 wf = pA2[2 * 64];                                          \
      e0 = MFMA16(wf, as_s8(Pw2_0), e0, 0, 0, 0);                             \
      e1 = MFMA16(wf, as_s8(Pw2_1), e1, 0, 0, 0); }                           \
    { const short8 wf = pA2[3 * 64];                                          \
      e0 = MFMA16(wf, as_s8(Pw3_0), e0, 0, 0, 0);                             \
      e1 = MFMA16(wf, as_s8(Pw3_1), e1, 0, 0, 0); }                           \
    EPILOG(0, z0 + (n),     rv_c0);                                           \
    EPILOG(1, z0 + (n) + 1, rv_c1);                                           \
    rv_c0 = rvn0; rv_c1 = rvn1;                                               \
} while (0)

    // warmup: partials for planes z0-1 (LA), z0 (LB); prefetch z0+1 (LA),
    // z0+2 (LB); rv for outputs z0, z0+1
    LOADP(z0 - 1, LA);
    PARTIALS(PA, LA);
    LOADP(z0, LB);
    PARTIALS(PB, LB);
    LOADP(z0 + 1, LA);
    LOADP(z0 + 2, LB);
    float rv_c0 = ru[((b * 64 + z0) * 64 + y) * 64 + wx];
    float rv_c1 = ru[((b * 64 + z0 + 1) * 64 + y) * 64 + wx];

    STEP2(PA, PB, PC, 0);
    STEP2(PC, PA, PB, 2);
    STEP2(PB, PC, PA, 4);
    STEP2(PA, PB, PC, 6);
    STEP2(PC, PA, PB, 8);
    STEP2(PB, PC, PA, 10);
    STEP2(PA, PB, PC, 12);
    STEP2(PC, PA, PB, 14);

#undef STEP2
#undef EPILOG
#undef COMBINE
#undef PARTIALS
#undef LOADP
}

// pass2: out *= (pre & post) -- multiplying by 1 is identity, so only dead
// voxels need touching, and they need zeros (no read of out needed).
__global__ __launch_bounds__(256) void nca_pass2(
    const float* __restrict__ alpha_new, const float* __restrict__ pre_life,
    float* __restrict__ out)
{
    const int idx = blockIdx.x * 256 + threadIdx.x;
    const int wx = idx & 63;
    const int hy = (idx >> 6) & 63;
    const int dz = (idx >> 12) & 63;

    float m = -1e30f;
    #pragma unroll
    for (int i = 0; i < 3; i++) {
        const int zz = dz + i - 1;
        if ((unsigned)zz >= 64u) continue;
        #pragma unroll
        for (int j = 0; j < 3; j++) {
            const int yy = hy + j - 1;
            if ((unsigned)yy >= 64u) continue;
            #pragma unroll
            for (int k = 0; k < 3; k++) {
                const int xx = wx + k - 1;
                if ((unsigned)xx >= 64u) continue;
                m = fmaxf(m, alpha_new[idx + (i - 1) * 4096 + (j - 1) * 64 + (k - 1)]);
            }
        }
    }
    const bool life = (m > 0.1f) && (pre_life[idx] > 0.5f);
    if (!life) {
        const float4 z = make_float4(0.0f, 0.0f, 0.0f, 0.0f);
        float4* p = (float4*)(out + (size_t)idx * CH);
        p[0] = z; p[1] = z; p[2] = z; p[3] = z;
    }
}

extern "C" void kernel_launch(void* const* d_in, const int* in_sizes, int n_in,
                              void* d_out, int out_size, void* d_ws, size_t ws_size,
                              hipStream_t stream) {
    const float* x  = (const float*)d_in[0];
    const float* w1 = (const float*)d_in[1];
    const float* b1 = (const float*)d_in[2];
    const float* w2 = (const float*)d_in[3];
    const float* b2 = (const float*)d_in[4];
    const float* ru = (const float*)d_in[5];
    float* out = (float*)d_out;

    float* alpha_new = (float*)d_ws;
    float* pre_life  = alpha_new + NVOX;

    // 256 blocks of 1024 threads: block = (b, y); 16 waves = 4 x-tiles x 4 z-chunks
    hipLaunchKernelGGL(nca_pass1, dim3(256), dim3(1024), 0, stream,
                       x, w1, b1, w2, b2, ru, out, alpha_new, pre_life);
    hipLaunchKernelGGL(nca_pass2, dim3(NVOX / 256), dim3(256), 0, stream,
                       alpha_new, pre_life, out);
}

// Round 25
// 340.275 us; speedup vs baseline: 1.0168x; 1.0168x over previous
//
#include <hip/hip_runtime.h>
#include <hip/hip_bf16.h>

#define CH   16
#define HID  128
#define DIM  64
#define NVOX (4 * DIM * DIM * DIM)

typedef __attribute__((ext_vector_type(8))) short short8;
typedef __attribute__((ext_vector_type(4))) float f32x4;
typedef __attribute__((ext_vector_type(2))) float f32x2;
typedef __attribute__((ext_vector_type(4))) unsigned int u32x4;

#define MFMA16 __builtin_amdgcn_mfma_f32_16x16x32_bf16

// sched_barrier mask: allow ALU|VALU|SALU|MFMA|DS to cross, pin VMEM above.
#define SB_PIN_VMEM_ONLY 0x38F

// zero row for OOB neighborhood reads (never written; .rodata zeros)
__device__ __align__(16) const float g_zrow[1024] = {};

__device__ __forceinline__ unsigned short f2bf(float f) {
    return __bfloat16_as_ushort(__float2bfloat16(f));   // staging only
}

// native packed cvt: dst = {bf16(hi)<<16 | bf16(lo)} (RNE) -- 1 instr for 2 vals
__device__ __forceinline__ unsigned int cvtpk(float lo, float hi) {
    unsigned int r;
    asm("v_cvt_pk_bf16_f32 %0, %1, %2" : "=v"(r) : "v"(lo), "v"(hi));
    return r;
}
__device__ __forceinline__ short8 as_s8(u32x4 v) {
    return __builtin_bit_cast(short8, v);
}

// ---- forced VOP3P packed-f32 (R19, kept: neutral, not harmful) ----
__device__ __forceinline__ f32x2 pk_add(f32x2 a, f32x2 b) {
    f32x2 r;
    asm("v_pk_add_f32 %0, %1, %2" : "=v"(r) : "v"(a), "v"(b));
    return r;
}
__device__ __forceinline__ f32x2 pk_sub(f32x2 a, f32x2 b) {   // a - b
    f32x2 r;
    asm("v_pk_add_f32 %0, %1, %2 neg_lo:[0,1] neg_hi:[0,1]"
        : "=v"(r) : "v"(a), "v"(b));
    return r;
}
__device__ __forceinline__ f32x2 pk_mul(f32x2 a, f32x2 b) {
    f32x2 r;
    asm("v_pk_mul_f32 %0, %1, %2" : "=v"(r) : "v"(a), "v"(b));
    return r;
}
__device__ __forceinline__ f32x2 pk_fma(f32x2 a, f32x2 b, f32x2 c) { // a*b+c
    f32x2 r;
    asm("v_pk_fma_f32 %0, %1, %2, %3" : "=v"(r) : "v"(a), "v"(b), "v"(c));
    return r;
}

struct V4 { f32x2 lo, hi; };
__device__ __forceinline__ V4 toV4(f32x4 v) {
    return V4{ f32x2{v[0], v[1]}, f32x2{v[2], v[3]} };
}
__device__ __forceinline__ V4 vadd(V4 a, V4 b){
    return V4{ pk_add(a.lo, b.lo), pk_add(a.hi, b.hi) };
}
__device__ __forceinline__ V4 vsub(V4 a, V4 b){
    return V4{ pk_sub(a.lo, b.lo), pk_sub(a.hi, b.hi) };
}
__device__ __forceinline__ V4 vfma2(V4 a, V4 b){       // b + 2*a
    const f32x2 two = {2.0f, 2.0f};
    return V4{ pk_fma(two, a.lo, b.lo), pk_fma(two, a.hi, b.hi) };
}
__device__ __forceinline__ V4 vmask(V4 a, float s){
    const f32x2 ss = {s, s};
    return V4{ pk_mul(a.lo, ss), pk_mul(a.hi, ss) };
}

struct Plane { V4 ps, pda, pds, vb; float pmax; };

// R25: R22's 1024-thread single-block-per-CU structure with NO launch
// attribute at all. Pattern established: ANY explicit occupancy attribute
// (launch_bounds 2nd arg / launch_bounds(1024) / waves_per_eu) activates the
// occupancy heuristic -> VGPR=64 -> spill (R4/R6/R22/R24). But hipcc's
// DEFAULT flat-work-group-size is (1,1024): unattributed kernels are already
// launchable at 1024 threads with VGPR capped at 128 -- and the allocator
// chose 120 for this body in R23. So unattributed + 1024-thread launch
// should give VGPR~120, no spill, and the forced 16-wave/CU residency that
// R22 proved (occupancy 43.6%) is achievable.
// Register hoist of W-frags abandoned (R14/R15 deterministic miscompile).
__global__ void nca_pass1(
    const float* __restrict__ x,  const float* __restrict__ w1,
    const float* __restrict__ b1, const float* __restrict__ w2,
    const float* __restrict__ b2, const float* __restrict__ ru,
    float* __restrict__ out, float* __restrict__ alpha_new,
    float* __restrict__ pre_life)
{
    __shared__ __align__(16) unsigned short sA1[8192];  // [n][h][g][m][j] 16KB
    __shared__ __align__(16) unsigned short sA2[2048];  // [s][g][m][j]     4KB
    __shared__ __align__(16) float sb1[HID];
    __shared__ __align__(16) float sb2[CH];

    for (int t = threadIdx.x; t < 8192; t += 1024) {
        const int j = t & 7, mm = (t >> 3) & 15, gg = (t >> 7) & 3,
                  hh = (t >> 9) & 1, nn = t >> 10;
        const int op  = 2 * hh + (j & 1);
        const int row = 16 * gg + 4 * (j >> 1) + op;                // kappa1
        float wv = w1[row * HID + 16 * nn + mm];
        if (op) wv *= (1.0f / 32.0f);       // fold sobel 1/32 into W1
        sA1[t] = f2bf(wv);
    }
    for (int t = threadIdx.x; t < 2048; t += 1024) {
        const int j = t & 7, mm = (t >> 3) & 15, gg = (t >> 7) & 3, ss = t >> 9;
        const int kk = 32 * ss + 16 * (j >> 2) + 4 * gg + (j & 3);  // kappa2
        sA2[t] = f2bf(w2[kk * CH + mm]);
    }
    if (threadIdx.x < HID) sb1[threadIdx.x] = b1[threadIdx.x];
    if (threadIdx.x < CH)  sb2[threadIdx.x] = b2[threadIdx.x];
    __syncthreads();

    const int lane = threadIdx.x & 63;
    const int wid  = __builtin_amdgcn_readfirstlane(threadIdx.x >> 6); // 0..15
    const int m = lane & 15;
    const int g = lane >> 4;

    // XCD-chunked swizzle (bijective: 256 % 8 == 0); block = (b, y)
    const unsigned pbid = blockIdx.x;
    const unsigned lbid = (pbid & 7) * 32 + (pbid >> 3);

    const int y  = lbid & 63;
    const int b  = lbid >> 6;
    const int zc = wid >> 2;            // wave's z-chunk (0..3)
    const int z0 = zc << 4;

    const short8* pA1 = ((const short8*)sA1) + (g * 16 + m);
    const short8* pA2 = ((const short8*)sA2) + (g * 16 + m);
    const float*  pb1 = sb1 + 4 * g;
    const float*  pb2 = sb2 + 4 * g;

    const int wx = 16 * (wid & 3) + m;  // wave's x-tile (0..3)
    const float ok0 = (wx > 0)  ? 1.0f : 0.0f;
    const float ok2 = (wx < 63) ? 1.0f : 0.0f;
    const int o1 = wx * CH + 4 * g;
    const int o0 = (wx > 0  ? wx - 1 : 0 ) * CH + 4 * g;
    const int o2 = (wx < 63 ? wx + 1 : 63) * CH + 4 * g;

    f32x4 LA[3][3], LB[3][3];   // two plane tap buffers
    Plane PA{}, PB{}, PC{};

#define LOADP(zz, L) do {                                                     \
    const bool zok = ((unsigned)(zz)) < 64u;                                  \
    const float* bp = x + ((size_t)(b * 64 + (zz))) * 65536;                  \
    const float* r0 = (zok && y > 0)  ? bp + (size_t)(y - 1) * 1024 : g_zrow; \
    const float* r1 =  zok            ? bp + (size_t)y * 1024       : g_zrow; \
    const float* r2 = (zok && y < 63) ? bp + (size_t)(y + 1) * 1024 : g_zrow; \
    L[0][0] = *(const f32x4*)(r0 + o0); L[0][1] = *(const f32x4*)(r0 + o1);   \
    L[0][2] = *(const f32x4*)(r0 + o2);                                       \
    L[1][0] = *(const f32x4*)(r1 + o0); L[1][1] = *(const f32x4*)(r1 + o1);   \
    L[1][2] = *(const f32x4*)(r1 + o2);                                       \
    L[2][0] = *(const f32x4*)(r2 + o0); L[2][1] = *(const f32x4*)(r2 + o1);   \
    L[2][2] = *(const f32x4*)(r2 + o2);                                       \
} while (0)

#define PARTIALS(P, L) do {                                                   \
    V4 s0, s1, s2, d0, d1, d2; float pm;                                      \
    { V4 va = vmask(toV4(L[0][0]), ok0), vb = toV4(L[0][1]),                  \
         vc = vmask(toV4(L[0][2]), ok2);                                      \
      s0 = vfma2(vb, vadd(va, vc)); d0 = vsub(va, vc);                        \
      pm = fmaxf(fmaxf(va.hi[1], vb.hi[1]), vc.hi[1]); }                      \
    { V4 va = vmask(toV4(L[1][0]), ok0), vb = toV4(L[1][1]),                  \
         vc = vmask(toV4(L[1][2]), ok2);                                      \
      s1 = vfma2(vb, vadd(va, vc)); d1 = vsub(va, vc);                        \
      pm = fmaxf(pm, fmaxf(fmaxf(va.hi[1], vb.hi[1]), vc.hi[1]));             \
      (P).vb = vb; }                                                          \
    { V4 va = vmask(toV4(L[2][0]), ok0), vb = toV4(L[2][1]),                  \
         vc = vmask(toV4(L[2][2]), ok2);                                      \
      s2 = vfma2(vb, vadd(va, vc)); d2 = vsub(va, vc);                        \
      pm = fmaxf(pm, fmaxf(fmaxf(va.hi[1], vb.hi[1]), vc.hi[1])); }           \
    (P).ps  = vfma2(s1, vadd(s0, s2));                                        \
    (P).pda = vsub(s0, s2);                                                   \
    (P).pds = vfma2(d1, vadd(d0, d2));                                        \
    (P).pmax = pm;                                                            \
} while (0)

// builds a0_S/a1_S (MFMA B-frags), cen_S, pm_S for one output plane
#define COMBINE(Pm1, P0, Pp1, S)                                              \
    const V4 zA_##S = vsub((Pm1).ps, (Pp1).ps);                               \
    const V4 zB_##S = vfma2((P0).pda, vadd((Pm1).pda, (Pp1).pda));            \
    const V4 zC_##S = vfma2((P0).pds, vadd((Pm1).pds, (Pp1).pds));            \
    const V4 cen_##S = (P0).vb;                                               \
    const float pm_##S = fmaxf(fmaxf((Pm1).pmax, (P0).pmax), (Pp1).pmax);     \
    const u32x4 A0_##S = { cvtpk(cen_##S.lo[0], zA_##S.lo[0]),                \
                           cvtpk(cen_##S.lo[1], zA_##S.lo[1]),                \
                           cvtpk(cen_##S.hi[0], zA_##S.hi[0]),                \
                           cvtpk(cen_##S.hi[1], zA_##S.hi[1]) };              \
    const u32x4 A1_##S = { cvtpk(zB_##S.lo[0], zC_##S.lo[0]),                 \
                           cvtpk(zB_##S.lo[1], zC_##S.lo[1]),                 \
                           cvtpk(zB_##S.hi[0], zC_##S.hi[0]),                 \
                           cvtpk(zB_##S.hi[1], zC_##S.hi[1]) };               \
    const short8 a0_##S = as_s8(A0_##S), a1_##S = as_s8(A1_##S);

#define EPILOG(S, zn, rvc) do {                                               \
    const int vox = ((b * 64 + (zn)) * 64 + y) * 64 + wx;                     \
    const float mk = ((rvc) <= 0.5f) ? 1.0f : 0.0f;                           \
    f32x4 xn;                                                                 \
    xn[0] = fmaf(e##S[0], mk, cen_##S.lo[0]);                                 \
    xn[1] = fmaf(e##S[1], mk, cen_##S.lo[1]);                                 \
    xn[2] = fmaf(e##S[2], mk, cen_##S.hi[0]);                                 \
    xn[3] = fmaf(e##S[3], mk, cen_##S.hi[1]);                                 \
    *(f32x4*)(out + (size_t)vox * CH + 4 * g) = xn;                           \
    if (g == 0) {                                                             \
        alpha_new[vox] = xn[3];                                               \
        pre_life[vox]  = (pm_##S > 0.1f) ? 1.0f : 0.0f;                       \
    }                                                                         \
} while (0)

// one z-PAIR: outputs n and n+1, single pass over W1/W2 LDS fragments
#define STEP2(Pm1, P0, Pp1, n) do {                                           \
    PARTIALS(Pp1, LA);                   /* plane n+1 */                      \
    COMBINE(Pm1, P0, Pp1, 0)             /* output n; Pm1 dead after */       \
    PARTIALS(Pm1, LB);                   /* plane n+2 -> dead slot */         \
    COMBINE(P0, Pp1, Pm1, 1)             /* output n+1 */                     \
    float rvn0 = 0.0f, rvn1 = 0.0f;                                           \
    if ((n) < 14) {                                                           \
        LOADP(z0 + (n) + 3, LA);                                              \
        LOADP(z0 + (n) + 4, LB);                                              \
        rvn0 = ru[((b * 64 + (z0 + (n) + 2)) * 64 + y) * 64 + wx];            \
        rvn1 = ru[((b * 64 + (z0 + (n) + 3)) * 64 + y) * 64 + wx];            \
    }                                                                         \
    __builtin_amdgcn_sched_barrier(SB_PIN_VMEM_ONLY);                         \
    u32x4 Pw0_0={},Pw1_0={},Pw2_0={},Pw3_0={};                                \
    u32x4 Pw0_1={},Pw1_1={},Pw2_1={},Pw3_1={};                                \
    _Pragma("unroll")                                                         \
    for (int nn = 0; nn < 8; nn++) {                                          \
        const short8 wA = pA1[(2 * nn + 0) * 64];   /* read ONCE, use 2x */   \
        const short8 wB = pA1[(2 * nn + 1) * 64];                             \
        const f32x4 bias = *(const f32x4*)(pb1 + 16 * nn);                    \
        f32x4 h0 = bias, h1 = bias;                                           \
        h0 = MFMA16(wA, a0_0, h0, 0, 0, 0); h0 = MFMA16(wB, a1_0, h0, 0, 0, 0); \
        h1 = MFMA16(wA, a0_1, h1, 0, 0, 0); h1 = MFMA16(wB, a1_1, h1, 0, 0, 0); \
        const unsigned w00 = cvtpk(fmaxf(h0[0], 0.0f), fmaxf(h0[1], 0.0f));   \
        const unsigned w01 = cvtpk(fmaxf(h0[2], 0.0f), fmaxf(h0[3], 0.0f));   \
        const unsigned w10 = cvtpk(fmaxf(h1[0], 0.0f), fmaxf(h1[1], 0.0f));   \
        const unsigned w11 = cvtpk(fmaxf(h1[2], 0.0f), fmaxf(h1[3], 0.0f));   \
        const int hi = (nn & 1) << 1;                                         \
        if (nn >> 1 == 0)      { Pw0_0[hi]=w00; Pw0_0[hi+1]=w01;              \
                                 Pw0_1[hi]=w10; Pw0_1[hi+1]=w11; }            \
        else if (nn >> 1 == 1) { Pw1_0[hi]=w00; Pw1_0[hi+1]=w01;              \
                                 Pw1_1[hi]=w10; Pw1_1[hi+1]=w11; }            \
        else if (nn >> 1 == 2) { Pw2_0[hi]=w00; Pw2_0[hi+1]=w01;              \
                                 Pw2_1[hi]=w10; Pw2_1[hi+1]=w11; }            \
        else                   { Pw3_0[hi]=w00; Pw3_0[hi+1]=w01;              \
                                 Pw3_1[hi]=w10; Pw3_1[hi+1]=w11; }            \
    }                                                                         \
    const f32x4 eb = *(const f32x4*)pb2;                                      \
    f32x4 e0 = eb, e1 = eb;                                                   \
    { const short8 wf = pA2[0 * 64];                                          \
      e0 = MFMA16(wf, as_s8(Pw0_0), e0, 0, 0, 0);                             \
      e1 = MFMA16(wf, as_s8(Pw0_1), e1, 0, 0, 0); }                           \
    { const short8 wf = pA2[1 * 64];                                          \
      e0 = MFMA16(wf, as_s8(Pw1_0), e0, 0, 0, 0);                             \
      e1 = MFMA16(wf, as_s8(Pw1_1), e1, 0, 0, 0); }                           \
    { const short8 wf = pA2[2 * 64];                                          \
      e0 = MFMA16(wf, as_s8(Pw2_0), e0, 0, 0, 0);                             \
      e1 = MFMA16(wf, as_s8(Pw2_1), e1, 0, 0, 0); }                           \
    { const short8 wf = pA2[3 * 64];                                          \
      e0 = MFMA16(wf, as_s8(Pw3_0), e0, 0, 0, 0);                             \
      e1 = MFMA16(wf, as_s8(Pw3_1), e1, 0, 0, 0); }                           \
    EPILOG(0, z0 + (n),     rv_c0);                                           \
    EPILOG(1, z0 + (n) + 1, rv_c1);                                           \
    rv_c0 = rvn0; rv_c1 = rvn1;                                               \
} while (0)

    // warmup: partials for planes z0-1 (LA), z0 (LB); prefetch z0+1 (LA),
    // z0+2 (LB); rv for outputs z0, z0+1
    LOADP(z0 - 1, LA);
    PARTIALS(PA, LA);
    LOADP(z0, LB);
    PARTIALS(PB, LB);
    LOADP(z0 + 1, LA);
    LOADP(z0 + 2, LB);
    float rv_c0 = ru[((b * 64 + z0) * 64 + y) * 64 + wx];
    float rv_c1 = ru[((b * 64 + z0 + 1) * 64 + y) * 64 + wx];

    STEP2(PA, PB, PC, 0);
    STEP2(PC, PA, PB, 2);
    STEP2(PB, PC, PA, 4);
    STEP2(PA, PB, PC, 6);
    STEP2(PC, PA, PB, 8);
    STEP2(PB, PC, PA, 10);
    STEP2(PA, PB, PC, 12);
    STEP2(PC, PA, PB, 14);

#undef STEP2
#undef EPILOG
#undef COMBINE
#undef PARTIALS
#undef LOADP
}

// pass2: out *= (pre & post) -- multiplying by 1 is identity, so only dead
// voxels need touching, and they need zeros (no read of out needed).
__global__ __launch_bounds__(256) void nca_pass2(
    const float* __restrict__ alpha_new, const float* __restrict__ pre_life,
    float* __restrict__ out)
{
    const int idx = blockIdx.x * 256 + threadIdx.x;
    const int wx = idx & 63;
    const int hy = (idx >> 6) & 63;
    const int dz = (idx >> 12) & 63;

    float m = -1e30f;
    #pragma unroll
    for (int i = 0; i < 3; i++) {
        const int zz = dz + i - 1;
        if ((unsigned)zz >= 64u) continue;
        #pragma unroll
        for (int j = 0; j < 3; j++) {
            const int yy = hy + j - 1;
            if ((unsigned)yy >= 64u) continue;
            #pragma unroll
            for (int k = 0; k < 3; k++) {
                const int xx = wx + k - 1;
                if ((unsigned)xx >= 64u) continue;
                m = fmaxf(m, alpha_new[idx + (i - 1) * 4096 + (j - 1) * 64 + (k - 1)]);
            }
        }
    }
    const bool life = (m > 0.1f) && (pre_life[idx] > 0.5f);
    if (!life) {
        const float4 z = make_float4(0.0f, 0.0f, 0.0f, 0.0f);
        float4* p = (float4*)(out + (size_t)idx * CH);
        p[0] = z; p[1] = z; p[2] = z; p[3] = z;
    }
}

extern "C" void kernel_launch(void* const* d_in, const int* in_sizes, int n_in,
                              void* d_out, int out_size, void* d_ws, size_t ws_size,
                              hipStream_t stream) {
    const float* x  = (const float*)d_in[0];
    const float* w1 = (const float*)d_in[1];
    const float* b1 = (const float*)d_in[2];
    const float* w2 = (const float*)d_in[3];
    const float* b2 = (const float*)d_in[4];
    const float* ru = (const float*)d_in[5];
    float* out = (float*)d_out;

    float* alpha_new = (float*)d_ws;
    float* pre_life  = alpha_new + NVOX;

    // 256 blocks of 1024 threads: block = (b, y); 16 waves = 4 x-tiles x 4 z-chunks
    hipLaunchKernelGGL(nca_pass1, dim3(256), dim3(1024), 0, stream,
                       x, w1, b1, w2, b2, ru, out, alpha_new, pre_life);
    hipLaunchKernelGGL(nca_pass2, dim3(NVOX / 256), dim3(256), 0, stream,
                       alpha_new, pre_life, out);
}

// Round 26
// 79.477 us; speedup vs baseline: 4.3534x; 4.2814x over previous
//
#include <hip/hip_runtime.h>
#include <hip/hip_bf16.h>

#define CH   16
#define HID  128
#define DIM  64
#define NVOX (4 * DIM * DIM * DIM)

typedef __attribute__((ext_vector_type(8))) short short8;
typedef __attribute__((ext_vector_type(4))) float f32x4;
typedef __attribute__((ext_vector_type(2))) float f32x2;
typedef __attribute__((ext_vector_type(4))) unsigned int u32x4;

#define MFMA16 __builtin_amdgcn_mfma_f32_16x16x32_bf16

// sched_barrier mask: allow ALU|VALU|SALU|MFMA|DS to cross, pin VMEM above.
#define SB_PIN_VMEM_ONLY 0x38F

// zero row for OOB neighborhood reads (never written; .rodata zeros)
__device__ __align__(16) const float g_zrow[1024] = {};

__device__ __forceinline__ unsigned short f2bf(float f) {
    return __bfloat16_as_ushort(__float2bfloat16(f));   // staging only
}

// native packed cvt: dst = {bf16(hi)<<16 | bf16(lo)} (RNE) -- 1 instr for 2 vals
__device__ __forceinline__ unsigned int cvtpk(float lo, float hi) {
    unsigned int r;
    asm("v_cvt_pk_bf16_f32 %0, %1, %2" : "=v"(r) : "v"(lo), "v"(hi));
    return r;
}
__device__ __forceinline__ short8 as_s8(u32x4 v) {
    return __builtin_bit_cast(short8, v);
}

// ---- forced VOP3P packed-f32 (R19, kept: neutral, not harmful) ----
__device__ __forceinline__ f32x2 pk_add(f32x2 a, f32x2 b) {
    f32x2 r;
    asm("v_pk_add_f32 %0, %1, %2" : "=v"(r) : "v"(a), "v"(b));
    return r;
}
__device__ __forceinline__ f32x2 pk_sub(f32x2 a, f32x2 b) {   // a - b
    f32x2 r;
    asm("v_pk_add_f32 %0, %1, %2 neg_lo:[0,1] neg_hi:[0,1]"
        : "=v"(r) : "v"(a), "v"(b));
    return r;
}
__device__ __forceinline__ f32x2 pk_mul(f32x2 a, f32x2 b) {
    f32x2 r;
    asm("v_pk_mul_f32 %0, %1, %2" : "=v"(r) : "v"(a), "v"(b));
    return r;
}
__device__ __forceinline__ f32x2 pk_fma(f32x2 a, f32x2 b, f32x2 c) { // a*b+c
    f32x2 r;
    asm("v_pk_fma_f32 %0, %1, %2, %3" : "=v"(r) : "v"(a), "v"(b), "v"(c));
    return r;
}

struct V4 { f32x2 lo, hi; };
__device__ __forceinline__ V4 toV4(f32x4 v) {
    return V4{ f32x2{v[0], v[1]}, f32x2{v[2], v[3]} };
}
__device__ __forceinline__ V4 vadd(V4 a, V4 b){
    return V4{ pk_add(a.lo, b.lo), pk_add(a.hi, b.hi) };
}
__device__ __forceinline__ V4 vsub(V4 a, V4 b){
    return V4{ pk_sub(a.lo, b.lo), pk_sub(a.hi, b.hi) };
}
__device__ __forceinline__ V4 vfma2(V4 a, V4 b){       // b + 2*a
    const f32x2 two = {2.0f, 2.0f};
    return V4{ pk_fma(two, a.lo, b.lo), pk_fma(two, a.hi, b.hi) };
}
__device__ __forceinline__ V4 vmask(V4 a, float s){
    const f32x2 ss = {s, s};
    return V4{ pk_mul(a.lo, ss), pk_mul(a.hi, ss) };
}

struct Plane { V4 ps, pda, pds, vb; float pmax; };

// R26: R23 base (best: 82.4us, VGPR 120, 4 waves/SIMD fully overlapped,
// wall == per-wave chain latency) + T5 s_setprio(1) around the MFMA/cvt
// section. Our 4 waves/SIMD run BARRIER-FREE and drift out of phase ->
// genuine wave role diversity, T5's stated prerequisite (null only on
// lockstep kernels; +4-7% where phases differ). Zero numerics change.
// 1024-thr blocks unusable: ANY path to them (lb(1024)/waves_per_eu/
// unattributed default) gives VGPR=64 + spill (R22/R24/R25).
// Register hoist of W-frags abandoned (R14/R15 deterministic miscompile).
__global__ __launch_bounds__(512) void nca_pass1(
    const float* __restrict__ x,  const float* __restrict__ w1,
    const float* __restrict__ b1, const float* __restrict__ w2,
    const float* __restrict__ b2, const float* __restrict__ ru,
    float* __restrict__ out, float* __restrict__ alpha_new,
    float* __restrict__ pre_life)
{
    __shared__ __align__(16) unsigned short sA1[8192];  // [n][h][g][m][j] 16KB
    __shared__ __align__(16) unsigned short sA2[2048];  // [s][g][m][j]     4KB
    __shared__ __align__(16) float sb1[HID];
    __shared__ __align__(16) float sb2[CH];

    for (int t = threadIdx.x; t < 8192; t += 512) {
        const int j = t & 7, mm = (t >> 3) & 15, gg = (t >> 7) & 3,
                  hh = (t >> 9) & 1, nn = t >> 10;
        const int op  = 2 * hh + (j & 1);
        const int row = 16 * gg + 4 * (j >> 1) + op;                // kappa1
        float wv = w1[row * HID + 16 * nn + mm];
        if (op) wv *= (1.0f / 32.0f);       // fold sobel 1/32 into W1
        sA1[t] = f2bf(wv);
    }
    for (int t = threadIdx.x; t < 2048; t += 512) {
        const int j = t & 7, mm = (t >> 3) & 15, gg = (t >> 7) & 3, ss = t >> 9;
        const int kk = 32 * ss + 16 * (j >> 2) + 4 * gg + (j & 3);  // kappa2
        sA2[t] = f2bf(w2[kk * CH + mm]);
    }
    if (threadIdx.x < HID) sb1[threadIdx.x] = b1[threadIdx.x];
    if (threadIdx.x < CH)  sb2[threadIdx.x] = b2[threadIdx.x];
    __syncthreads();

    const int lane = threadIdx.x & 63;
    const int wid  = __builtin_amdgcn_readfirstlane(threadIdx.x >> 6); // 0..7
    const int m = lane & 15;
    const int g = lane >> 4;

    // XCD-chunked swizzle (bijective: 512 % 8 == 0); block = (b, y, z-half)
    const unsigned pbid = blockIdx.x;
    const unsigned lbid = (pbid & 7) * 64 + (pbid >> 3);

    const int zh = lbid & 1;            // z-half (0..1)
    const int y  = (lbid >> 1) & 63;
    const int b  = lbid >> 7;
    const int zc = (zh << 1) | (wid >> 2);   // z-chunk (0..3)
    const int z0 = zc << 4;

    const short8* pA1 = ((const short8*)sA1) + (g * 16 + m);
    const short8* pA2 = ((const short8*)sA2) + (g * 16 + m);
    const float*  pb1 = sb1 + 4 * g;
    const float*  pb2 = sb2 + 4 * g;

    const int wx = 16 * (wid & 3) + m;  // wave's x-tile (0..3)
    const float ok0 = (wx > 0)  ? 1.0f : 0.0f;
    const float ok2 = (wx < 63) ? 1.0f : 0.0f;
    const int o1 = wx * CH + 4 * g;
    const int o0 = (wx > 0  ? wx - 1 : 0 ) * CH + 4 * g;
    const int o2 = (wx < 63 ? wx + 1 : 63) * CH + 4 * g;

    f32x4 LA[3][3], LB[3][3];   // two plane tap buffers
    Plane PA{}, PB{}, PC{};

#define LOADP(zz, L) do {                                                     \
    const bool zok = ((unsigned)(zz)) < 64u;                                  \
    const float* bp = x + ((size_t)(b * 64 + (zz))) * 65536;                  \
    const float* r0 = (zok && y > 0)  ? bp + (size_t)(y - 1) * 1024 : g_zrow; \
    const float* r1 =  zok            ? bp + (size_t)y * 1024       : g_zrow; \
    const float* r2 = (zok && y < 63) ? bp + (size_t)(y + 1) * 1024 : g_zrow; \
    L[0][0] = *(const f32x4*)(r0 + o0); L[0][1] = *(const f32x4*)(r0 + o1);   \
    L[0][2] = *(const f32x4*)(r0 + o2);                                       \
    L[1][0] = *(const f32x4*)(r1 + o0); L[1][1] = *(const f32x4*)(r1 + o1);   \
    L[1][2] = *(const f32x4*)(r1 + o2);                                       \
    L[2][0] = *(const f32x4*)(r2 + o0); L[2][1] = *(const f32x4*)(r2 + o1);   \
    L[2][2] = *(const f32x4*)(r2 + o2);                                       \
} while (0)

#define PARTIALS(P, L) do {                                                   \
    V4 s0, s1, s2, d0, d1, d2; float pm;                                      \
    { V4 va = vmask(toV4(L[0][0]), ok0), vb = toV4(L[0][1]),                  \
         vc = vmask(toV4(L[0][2]), ok2);                                      \
      s0 = vfma2(vb, vadd(va, vc)); d0 = vsub(va, vc);                        \
      pm = fmaxf(fmaxf(va.hi[1], vb.hi[1]), vc.hi[1]); }                      \
    { V4 va = vmask(toV4(L[1][0]), ok0), vb = toV4(L[1][1]),                  \
         vc = vmask(toV4(L[1][2]), ok2);                                      \
      s1 = vfma2(vb, vadd(va, vc)); d1 = vsub(va, vc);                        \
      pm = fmaxf(pm, fmaxf(fmaxf(va.hi[1], vb.hi[1]), vc.hi[1]));             \
      (P).vb = vb; }                                                          \
    { V4 va = vmask(toV4(L[2][0]), ok0), vb = toV4(L[2][1]),                  \
         vc = vmask(toV4(L[2][2]), ok2);                                      \
      s2 = vfma2(vb, vadd(va, vc)); d2 = vsub(va, vc);                        \
      pm = fmaxf(pm, fmaxf(fmaxf(va.hi[1], vb.hi[1]), vc.hi[1])); }           \
    (P).ps  = vfma2(s1, vadd(s0, s2));                                        \
    (P).pda = vsub(s0, s2);                                                   \
    (P).pds = vfma2(d1, vadd(d0, d2));                                        \
    (P).pmax = pm;                                                            \
} while (0)

// builds a0_S/a1_S (MFMA B-frags), cen_S, pm_S for one output plane
#define COMBINE(Pm1, P0, Pp1, S)                                              \
    const V4 zA_##S = vsub((Pm1).ps, (Pp1).ps);                               \
    const V4 zB_##S = vfma2((P0).pda, vadd((Pm1).pda, (Pp1).pda));            \
    const V4 zC_##S = vfma2((P0).pds, vadd((Pm1).pds, (Pp1).pds));            \
    const V4 cen_##S = (P0).vb;                                               \
    const float pm_##S = fmaxf(fmaxf((Pm1).pmax, (P0).pmax), (Pp1).pmax);     \
    const u32x4 A0_##S = { cvtpk(cen_##S.lo[0], zA_##S.lo[0]),                \
                           cvtpk(cen_##S.lo[1], zA_##S.lo[1]),                \
                           cvtpk(cen_##S.hi[0], zA_##S.hi[0]),                \
                           cvtpk(cen_##S.hi[1], zA_##S.hi[1]) };              \
    const u32x4 A1_##S = { cvtpk(zB_##S.lo[0], zC_##S.lo[0]),                 \
                           cvtpk(zB_##S.lo[1], zC_##S.lo[1]),                 \
                           cvtpk(zB_##S.hi[0], zC_##S.hi[0]),                 \
                           cvtpk(zB_##S.hi[1], zC_##S.hi[1]) };               \
    const short8 a0_##S = as_s8(A0_##S), a1_##S = as_s8(A1_##S);

#define EPILOG(S, zn, rvc) do {                                               \
    const int vox = ((b * 64 + (zn)) * 64 + y) * 64 + wx;                     \
    const float mk = ((rvc) <= 0.5f) ? 1.0f : 0.0f;                           \
    f32x4 xn;                                                                 \
    xn[0] = fmaf(e##S[0], mk, cen_##S.lo[0]);                                 \
    xn[1] = fmaf(e##S[1], mk, cen_##S.lo[1]);                                 \
    xn[2] = fmaf(e##S[2], mk, cen_##S.hi[0]);                                 \
    xn[3] = fmaf(e##S[3], mk, cen_##S.hi[1]);                                 \
    *(f32x4*)(out + (size_t)vox * CH + 4 * g) = xn;                           \
    if (g == 0) {                                                             \
        alpha_new[vox] = xn[3];                                               \
        pre_life[vox]  = (pm_##S > 0.1f) ? 1.0f : 0.0f;                       \
    }                                                                         \
} while (0)

// one z-PAIR: outputs n and n+1, single pass over W1/W2 LDS fragments
#define STEP2(Pm1, P0, Pp1, n) do {                                           \
    PARTIALS(Pp1, LA);                   /* plane n+1 */                      \
    COMBINE(Pm1, P0, Pp1, 0)             /* output n; Pm1 dead after */       \
    PARTIALS(Pm1, LB);                   /* plane n+2 -> dead slot */         \
    COMBINE(P0, Pp1, Pm1, 1)             /* output n+1 */                     \
    float rvn0 = 0.0f, rvn1 = 0.0f;                                           \
    if ((n) < 14) {                                                           \
        LOADP(z0 + (n) + 3, LA);                                              \
        LOADP(z0 + (n) + 4, LB);                                              \
        rvn0 = ru[((b * 64 + (z0 + (n) + 2)) * 64 + y) * 64 + wx];            \
        rvn1 = ru[((b * 64 + (z0 + (n) + 3)) * 64 + y) * 64 + wx];            \
    }                                                                         \
    __builtin_amdgcn_sched_barrier(SB_PIN_VMEM_ONLY);                         \
    __builtin_amdgcn_s_setprio(1);       /* T5: favor MFMA-section wave */    \
    u32x4 Pw0_0={},Pw1_0={},Pw2_0={},Pw3_0={};                                \
    u32x4 Pw0_1={},Pw1_1={},Pw2_1={},Pw3_1={};                                \
    _Pragma("unroll")                                                         \
    for (int nn = 0; nn < 8; nn++) {                                          \
        const short8 wA = pA1[(2 * nn + 0) * 64];   /* read ONCE, use 2x */   \
        const short8 wB = pA1[(2 * nn + 1) * 64];                             \
        const f32x4 bias = *(const f32x4*)(pb1 + 16 * nn);                    \
        f32x4 h0 = bias, h1 = bias;                                           \
        h0 = MFMA16(wA, a0_0, h0, 0, 0, 0); h0 = MFMA16(wB, a1_0, h0, 0, 0, 0); \
        h1 = MFMA16(wA, a0_1, h1, 0, 0, 0); h1 = MFMA16(wB, a1_1, h1, 0, 0, 0); \
        const unsigned w00 = cvtpk(fmaxf(h0[0], 0.0f), fmaxf(h0[1], 0.0f));   \
        const unsigned w01 = cvtpk(fmaxf(h0[2], 0.0f), fmaxf(h0[3], 0.0f));   \
        const unsigned w10 = cvtpk(fmaxf(h1[0], 0.0f), fmaxf(h1[1], 0.0f));   \
        const unsigned w11 = cvtpk(fmaxf(h1[2], 0.0f), fmaxf(h1[3], 0.0f));   \
        const int hi = (nn & 1) << 1;                                         \
        if (nn >> 1 == 0)      { Pw0_0[hi]=w00; Pw0_0[hi+1]=w01;              \
                                 Pw0_1[hi]=w10; Pw0_1[hi+1]=w11; }            \
        else if (nn >> 1 == 1) { Pw1_0[hi]=w00; Pw1_0[hi+1]=w01;              \
                                 Pw1_1[hi]=w10; Pw1_1[hi+1]=w11; }            \
        else if (nn >> 1 == 2) { Pw2_0[hi]=w00; Pw2_0[hi+1]=w01;              \
                                 Pw2_1[hi]=w10; Pw2_1[hi+1]=w11; }            \
        else                   { Pw3_0[hi]=w00; Pw3_0[hi+1]=w01;              \
                                 Pw3_1[hi]=w10; Pw3_1[hi+1]=w11; }            \
    }                                                                         \
    const f32x4 eb = *(const f32x4*)pb2;                                      \
    f32x4 e0 = eb, e1 = eb;                                                   \
    { const short8 wf = pA2[0 * 64];                                          \
      e0 = MFMA16(wf, as_s8(Pw0_0), e0, 0, 0, 0);                             \
      e1 = MFMA16(wf, as_s8(Pw0_1), e1, 0, 0, 0); }                           \
    { const short8 wf = pA2[1 * 64];                                          \
      e0 = MFMA16(wf, as_s8(Pw1_0), e0, 0, 0, 0);                             \
      e1 = MFMA16(wf, as_s8(Pw1_1), e1, 0, 0, 0); }                           \
    { const short8 wf = pA2[2 * 64];                                          \
      e0 = MFMA16(wf, as_s8(Pw2_0), e0, 0, 0, 0);                             \
      e1 = MFMA16(wf, as_s8(Pw2_1), e1, 0, 0, 0); }                           \
    { const short8 wf = pA2[3 * 64];                                          \
      e0 = MFMA16(wf, as_s8(Pw3_0), e0, 0, 0, 0);                             \
      e1 = MFMA16(wf, as_s8(Pw3_1), e1, 0, 0, 0); }                           \
    __builtin_amdgcn_s_setprio(0);                                            \
    EPILOG(0, z0 + (n),     rv_c0);                                           \
    EPILOG(1, z0 + (n) + 1, rv_c1);                                           \
    rv_c0 = rvn0; rv_c1 = rvn1;                                               \
} while (0)

    // warmup: partials for planes z0-1 (LA), z0 (LB); prefetch z0+1 (LA),
    // z0+2 (LB); rv for outputs z0, z0+1
    LOADP(z0 - 1, LA);
    PARTIALS(PA, LA);
    LOADP(z0, LB);
    PARTIALS(PB, LB);
    LOADP(z0 + 1, LA);
    LOADP(z0 + 2, LB);
    float rv_c0 = ru[((b * 64 + z0) * 64 + y) * 64 + wx];
    float rv_c1 = ru[((b * 64 + z0 + 1) * 64 + y) * 64 + wx];

    STEP2(PA, PB, PC, 0);
    STEP2(PC, PA, PB, 2);
    STEP2(PB, PC, PA, 4);
    STEP2(PA, PB, PC, 6);
    STEP2(PC, PA, PB, 8);
    STEP2(PB, PC, PA, 10);
    STEP2(PA, PB, PC, 12);
    STEP2(PC, PA, PB, 14);

#undef STEP2
#undef EPILOG
#undef COMBINE
#undef PARTIALS
#undef LOADP
}

// pass2: out *= (pre & post) -- multiplying by 1 is identity, so only dead
// voxels need touching, and they need zeros (no read of out needed).
__global__ __launch_bounds__(256) void nca_pass2(
    const float* __restrict__ alpha_new, const float* __restrict__ pre_life,
    float* __restrict__ out)
{
    const int idx = blockIdx.x * 256 + threadIdx.x;
    const int wx = idx & 63;
    const int hy = (idx >> 6) & 63;
    const int dz = (idx >> 12) & 63;

    float m = -1e30f;
    #pragma unroll
    for (int i = 0; i < 3; i++) {
        const int zz = dz + i - 1;
        if ((unsigned)zz >= 64u) continue;
        #pragma unroll
        for (int j = 0; j < 3; j++) {
            const int yy = hy + j - 1;
            if ((unsigned)yy >= 64u) continue;
            #pragma unroll
            for (int k = 0; k < 3; k++) {
                const int xx = wx + k - 1;
                if ((unsigned)xx >= 64u) continue;
                m = fmaxf(m, alpha_new[idx + (i - 1) * 4096 + (j - 1) * 64 + (k - 1)]);
            }
        }
    }
    const bool life = (m > 0.1f) && (pre_life[idx] > 0.5f);
    if (!life) {
        const float4 z = make_float4(0.0f, 0.0f, 0.0f, 0.0f);
        float4* p = (float4*)(out + (size_t)idx * CH);
        p[0] = z; p[1] = z; p[2] = z; p[3] = z;
    }
}

extern "C" void kernel_launch(void* const* d_in, const int* in_sizes, int n_in,
                              void* d_out, int out_size, void* d_ws, size_t ws_size,
                              hipStream_t stream) {
    const float* x  = (const float*)d_in[0];
    const float* w1 = (const float*)d_in[1];
    const float* b1 = (const float*)d_in[2];
    const float* w2 = (const float*)d_in[3];
    const float* b2 = (const float*)d_in[4];
    const float* ru = (const float*)d_in[5];
    float* out = (float*)d_out;

    float* alpha_new = (float*)d_ws;
    float* pre_life  = alpha_new + NVOX;

    // 512 blocks of 512 threads: block = (b, y, z-half); 8 waves =
    // 4 x-tiles x 2 z-chunks of 16
    hipLaunchKernelGGL(nca_pass1, dim3(512), dim3(512), 0, stream,
                       x, w1, b1, w2, b2, ru, out, alpha_new, pre_life);
    hipLaunchKernelGGL(nca_pass2, dim3(NVOX / 256), dim3(256), 0, stream,
                       alpha_new, pre_life, out);
}